// Round 12
// baseline (46.020 us; speedup 1.0000x reference)
//
#include <hip/hip_runtime.h>
#include <math.h>

#define DDIM 512
#define BDIM 256
#define NCLS 85742
#define NB1 2048
#define CHUNK1 ((NCLS + NB1 - 1) / NB1)   // 42 rows per block

typedef float f32x4 __attribute__((ext_vector_type(4)));

// ws float layout:
//   [0] Si_acc   [1] Sy_tot   [2] S2_tot   [8] arrival counter (uint)
//   [16..143]  aux sy partials (128)
//   [144..271] aux s2 partials (128)
//   [1024 .. +131072)  U: f32x4 [row(256)][quad(128)]  (512 KB)
//   then partialT: f32x4 [quad(128)][block(2048)]      (4 MB)
#define WS_UPART 1024
#define WS_PART  (1024 + 256 * 128 * 4)

__device__ __forceinline__ float wave_reduce(float v) {
    #pragma unroll
    for (int off = 32; off > 0; off >>= 1)
        v += __shfl_down(v, off, 64);
    return v;
}

__device__ __forceinline__ float block_reduce(float v, float* smem) {
    const int lane = threadIdx.x & 63;
    const int wid  = threadIdx.x >> 6;
    v = wave_reduce(v);
    if (lane == 0) smem[wid] = v;
    __syncthreads();
    if (wid == 0) {
        v = (lane < (int)(blockDim.x >> 6)) ? smem[lane] : 0.0f;
        v = wave_reduce(v);
    }
    return v;
}

// K1: identical to the 43.4us R9 kernel (contiguous 42-row chunk, 4-deep
// rotation, transposed partials, aux fold for blocks 0..127), plus zeroing
// the K2 arrival counter.
__global__ __launch_bounds__(256, 4)
void colsum_partial(const float* __restrict__ W, const float* __restrict__ mu,
                    const int* __restrict__ label, float* __restrict__ ws,
                    float* __restrict__ out) {
    const int t = threadIdx.x;
    const int b = blockIdx.x;
    if (b == 0 && t == 0) {
        ws[0] = 0.0f; *out = 0.0f;
        *reinterpret_cast<unsigned int*>(ws + 8) = 0u;
    }
    const int q = t & 127;
    const int rsub = t >> 7;
    const f32x4* __restrict__ W4 = reinterpret_cast<const f32x4*>(W) + q;

    const int r0 = b * CHUNK1;
    const int r1 = (r0 + CHUNK1 < NCLS) ? (r0 + CHUNK1) : NCLS;

    f32x4 a0 = (f32x4)(0.f), a1 = a0, a2 = a0, a3 = a0;

    if (r1 - r0 == CHUNK1) {
        const f32x4* base = W4 + (size_t)(r0 + rsub) * 128;  // unit = 2 rows
        f32x4 c0 = base[0];
        f32x4 c1 = base[256];
        f32x4 c2 = base[512];
        f32x4 c3 = base[768];
        #pragma unroll
        for (int k = 1; k <= 4; ++k) {
            const f32x4* p = base + (size_t)k * 1024;
            a0 += c0;  c0 = p[0];
            a1 += c1;  c1 = p[256];
            a2 += c2;  c2 = p[512];
            a3 += c3;  c3 = p[768];
        }
        f32x4 cl = base[5120];
        a0 += c0; a1 += c1; a2 += c2; a3 += c3;
        a0 += cl;
    } else {
        for (int r = r0 + rsub; r < r1; r += 2)
            a0 += W4[(size_t)r * 128];
    }
    a0 += a1 + a2 + a3;

    __shared__ f32x4 smem[128];
    if (rsub) smem[q] = a0;
    __syncthreads();
    if (!rsub) {
        a0 += smem[q];
        f32x4* partialT = reinterpret_cast<f32x4*>(ws + WS_PART);
        partialT[(size_t)q * NB1 + b] = a0;   // empty blocks write zeros
    }

    // ---- aux work: blocks 0..127, batch rows 2b, 2b+1 ----
    if (b < 128) {
        const int row = 2 * b + rsub;
        const int lab = label[row];
        const f32x4 m4 = reinterpret_cast<const f32x4*>(mu)[(size_t)row * 128 + q];
        const f32x4 w4 = reinterpret_cast<const f32x4*>(W)[(size_t)lab * 128 + q];
        f32x4 d = w4 - m4;
        f32x4 u = w4 + m4;
        reinterpret_cast<f32x4*>(ws + WS_UPART)[(size_t)row * 128 + q] = u;
        float syp = d.x * d.x + d.y * d.y + d.z * d.z + d.w * d.w;
        float s2p = u.x * u.x + u.y * u.y + u.z * u.z + u.w * u.w;
        __shared__ float rsm[8];
        __syncthreads();
        syp = block_reduce(syp, rsm);
        __syncthreads();
        s2p = block_reduce(s2p, rsm);
        if (t == 0) {
            ws[16 + b]  = syp;
            ws[144 + b] = s2p;
        }
    }
}

// K2 (fused with loss): 128 blocks. Phase A: block q finishes colsum for its
// 4 columns + its share of Si's expansion; block 0 reduces aux Sy/S2.
// Ticket barrier (128 blocks always co-resident -> deadlock-free, and the
// final scalars are order-independent -> deterministic). Phase B: all 128
// blocks compute the erf/erfc sum over std (one f32x4 per thread).
__global__ __launch_bounds__(256, 4)
void reduce_loss(float* __restrict__ ws, const float* __restrict__ stdv,
                 float* __restrict__ out) {
    const int q = blockIdx.x;       // 0..127
    const int t = threadIdx.x;
    const f32x4* __restrict__ partialT =
        reinterpret_cast<const f32x4*>(ws + WS_PART) + (size_t)q * NB1;
    f32x4 s = (f32x4)(0.f);
    #pragma unroll
    for (int k = 0; k < NB1 / 256; ++k)
        s += partialT[t + k * 256];
    f32x4 u = reinterpret_cast<const f32x4*>(ws + WS_UPART)[(size_t)t * 128 + q];

    float sx = wave_reduce(s.x), sy = wave_reduce(s.y);
    float sz = wave_reduce(s.z), sw = wave_reduce(s.w);
    float ux = wave_reduce(u.x), uy = wave_reduce(u.y);
    float uz = wave_reduce(u.z), uw = wave_reduce(u.w);
    __shared__ f32x4 sm[4], um[4];
    if ((t & 63) == 0) {
        sm[t >> 6] = (f32x4)(sx, sy, sz, sw);
        um[t >> 6] = (f32x4)(ux, uy, uz, uw);
    }
    __syncthreads();
    if (t == 0) {
        f32x4 cs = (sm[0] + sm[1]) + (sm[2] + sm[3]);
        f32x4 U  = (um[0] + um[1]) + (um[2] + um[3]);
        f32x4 si4 = 256.0f * cs * cs - 2.0f * cs * U;
        atomicAdd(&ws[0], si4.x + si4.y + si4.z + si4.w);
    }

    if (q == 0) {
        __syncthreads();
        __shared__ float rsm[8];
        float syp = (t < 128) ? ws[16 + t]  : 0.0f;
        float s2p = (t < 128) ? ws[144 + t] : 0.0f;
        syp = block_reduce(syp, rsm);
        __syncthreads();
        s2p = block_reduce(s2p, rsm);
        if (t == 0) { ws[1] = syp; ws[2] = s2p; }
    }

    // ---- ticket barrier across the 128 blocks ----
    __syncthreads();
    __shared__ float sc[3];
    unsigned int* cnt = reinterpret_cast<unsigned int*>(ws + 8);
    if (t == 0) {
        __threadfence();
        atomicAdd(cnt, 1u);
        while (__hip_atomic_load(cnt, __ATOMIC_ACQUIRE,
                                 __HIP_MEMORY_SCOPE_AGENT) < 128u) {}
        sc[0] = __hip_atomic_load(&ws[0], __ATOMIC_RELAXED, __HIP_MEMORY_SCOPE_AGENT);
        sc[1] = __hip_atomic_load(&ws[1], __ATOMIC_RELAXED, __HIP_MEMORY_SCOPE_AGENT);
        sc[2] = __hip_atomic_load(&ws[2], __ATOMIC_RELAXED, __HIP_MEMORY_SCOPE_AGENT);
    }
    __syncthreads();

    // ---- loss phase: 128 blocks x 256 threads x f32x4 = 131072 std elems ----
    const float dy = sqrtf(sc[1]);
    const float di = sqrtf(sc[0] + sc[2]);    // Si = Si_acc + S2
    const float inv_sqrt2 = 0.70710678118654752f;
    f32x4 s4 = reinterpret_cast<const f32x4*>(stdv)[q * 256 + t];
    float acc;
    {
        float rx = inv_sqrt2 / s4.x, ry = inv_sqrt2 / s4.y;
        float rz = inv_sqrt2 / s4.z, rw = inv_sqrt2 / s4.w;
        acc  = erff(dy * rx) + erfcf(di * rx);
        acc += erff(dy * ry) + erfcf(di * ry);
        acc += erff(dy * rz) + erfcf(di * rz);
        acc += erff(dy * rw) + erfcf(di * rw);
    }
    __shared__ float lsm[8];
    acc = block_reduce(acc, lsm);
    if (t == 0) atomicAdd(out, acc);
}

extern "C" void kernel_launch(void* const* d_in, const int* in_sizes, int n_in,
                              void* d_out, int out_size, void* d_ws, size_t ws_size,
                              hipStream_t stream) {
    // inputs: 0=x (unused), 1=mu, 2=std, 3=weight, 4=label
    const float* mu    = (const float*)d_in[1];
    const float* stdv  = (const float*)d_in[2];
    const float* W     = (const float*)d_in[3];
    const int*   label = (const int*)d_in[4];
    float* out = (float*)d_out;
    float* ws  = (float*)d_ws;

    colsum_partial<<<NB1, 256, 0, stream>>>(W, mu, label, ws, out);
    reduce_loss<<<128, 256, 0, stream>>>(ws, stdv, out);
}